// Round 5
// baseline (92.977 us; speedup 1.0000x reference)
//
#include <hip/hip_runtime.h>

#define NPTS 2048
#define NCP  32
#define P    4   // consecutive points per thread (float4 stores)
#define GB   2   // batches per block

// Binomial coefficients C(31, i) (exact)
static __device__ const float C31[NCP] = {
    1.f, 31.f, 465.f, 4495.f, 31465.f, 169911.f, 736281.f, 2629575.f,
    7888725.f, 20160075.f, 44352165.f, 84672315.f, 141120525.f, 206253075.f,
    265182525.f, 300540195.f, 300540195.f, 265182525.f, 206253075.f, 141120525.f,
    84672315.f, 44352165.f, 20160075.f, 7888725.f, 2629575.f, 736281.f,
    169911.f, 31465.f, 4495.f, 465.f, 31.f, 1.f
};

// Clamped knot vector value for knot index i (0..35): 4 zeros, interior
// (i-3)/29, 4 ones.
__device__ __forceinline__ float knq(int i) {
    int m = i - 3;
    m = m < 0 ? 0 : m;
    return (m >= 29) ? 1.0f : (float)m * (float)(1.0 / 29.0);
}

// P=4 points x GB=2 batches per thread. Each wave-uniform broadcast
// ds_read_b128 of control points feeds FMAs for 4 points (vs 1 at P=1):
// bezier DS drops 16 -> 4 instr per point-batch. Two phases (spline streamed
// per-g, then bezier) keep peak VGPR ~50 -> 8 waves/SIMD retained.
__global__ void __launch_bounds__(256, 8) fused_kernel(
    const float* __restrict__ bspline_cp, const float* __restrict__ nurbs_cp,
    const float* __restrict__ nurbs_w, const float* __restrict__ bezier_cp,
    float* __restrict__ out, int B) {
    const int tid = threadIdx.x;
    const int n0  = (blockIdx.x * 256 + tid) * P;   // first of this thread's 4 points
    const int b0  = blockIdx.y * GB;

    __shared__ float s_bs[GB * NCP * 2];
    __shared__ float s_nc[GB * NCP * 2];
    __shared__ float s_bz[GB * NCP * 2];
    __shared__ float s_w [GB * NCP];
    for (int idx = tid; idx < GB * NCP * 2; idx += 256) {
        s_bs[idx] = bspline_cp[(size_t)b0 * NCP * 2 + idx];
        s_nc[idx] = nurbs_cp[(size_t)b0 * NCP * 2 + idx];
        s_bz[idx] = bezier_cp[(size_t)b0 * NCP * 2 + idx];
    }
    for (int idx = tid; idx < GB * NCP; idx += 256)
        s_w[idx] = nurbs_w[(size_t)b0 * NCP + idx];
    __syncthreads();

    const unsigned cs = (unsigned)B * 2u * NPTS;   // per-curve output stride (fits 32b)

    // ---- Phase A: per-point t, span, cubic de Boor basis ----
    float tt[P];
    int   sp_[P];
    float bv[P][4];
#pragma unroll
    for (int p = 0; p < P; ++p) {
        const float t = (float)((double)(n0 + p) * (1.0 / (double)(NPTS - 1)));
        tt[p] = t;
        int s = (int)(t * 29.0f);
        s = s < 28 ? s : 28;
        sp_[p] = s;
        const int j = s + 3;             // knot-span: U[j] <= t < U[j+1]
        const float L1 = t - knq(j);
        const float R1 = knq(j + 1) - t;
        const float L2 = t - knq(j - 1);
        const float R2 = knq(j + 2) - t;
        const float L3 = t - knq(j - 2);
        const float R3 = knq(j + 3) - t;
        float N0, N1, N2, N3, tmp, sv;
        tmp = __builtin_amdgcn_rcpf(R1 + L1);
        N0 = R1 * tmp;
        N1 = L1 * tmp;
        tmp = N0 * __builtin_amdgcn_rcpf(R1 + L2);
        N0 = R1 * tmp;
        sv = L2 * tmp;
        tmp = N1 * __builtin_amdgcn_rcpf(R2 + L1);
        N1 = fmaf(R2, tmp, sv);
        N2 = L1 * tmp;
        tmp = N0 * __builtin_amdgcn_rcpf(R1 + L3);
        N0 = R1 * tmp;
        sv = L3 * tmp;
        tmp = N1 * __builtin_amdgcn_rcpf(R2 + L2);
        N1 = fmaf(R2, tmp, sv);
        sv = L2 * tmp;
        tmp = N2 * __builtin_amdgcn_rcpf(R3 + L1);
        N2 = fmaf(R3, tmp, sv);
        N3 = L1 * tmp;
        bv[p][0] = N0; bv[p][1] = N1; bv[p][2] = N2; bv[p][3] = N3;
    }

    // ---- Phase B: B-spline + NURBS sparse 4-term dots, streamed per g ----
#pragma unroll
    for (int g = 0; g < GB; ++g) {
        float4 bx, by, nx, ny;
        float* bxp = &bx.x; float* byp = &by.x;
        float* nxp = &nx.x; float* nyp = &ny.x;
#pragma unroll
        for (int p = 0; p < P; ++p) {
            float sbx = 0.f, sby = 0.f, snx = 0.f, sny = 0.f, den = 0.f;
#pragma unroll
            for (int k = 0; k < 4; ++k) {
                const int idx = sp_[p] + k;
                const float c = bv[p][k];
                float2 cb = *reinterpret_cast<const float2*>(&s_bs[g * 64 + idx * 2]);
                sbx = fmaf(c, cb.x, sbx); sby = fmaf(c, cb.y, sby);
                const float wb = c * s_w[g * 32 + idx];
                den += wb;
                float2 cn = *reinterpret_cast<const float2*>(&s_nc[g * 64 + idx * 2]);
                snx = fmaf(wb, cn.x, snx); sny = fmaf(wb, cn.y, sny);
            }
            const float inv = __builtin_amdgcn_rcpf(den + 1e-8f);
            bxp[p] = sbx; byp[p] = sby;
            nxp[p] = snx * inv; nyp[p] = sny * inv;
        }
        const unsigned base = (unsigned)(b0 + g) * 2u * NPTS + (unsigned)n0;
        *reinterpret_cast<float4*>(&out[base])             = bx;
        *reinterpret_cast<float4*>(&out[base + NPTS])      = by;
        *reinterpret_cast<float4*>(&out[cs + base])        = nx;
        *reinterpret_cast<float4*>(&out[cs + base + NPTS]) = ny;
    }

    // ---- Phase C: Bezier dense 32-term dot; basis exp2-in-register ----
    float dd[P], e0[P];
#pragma unroll
    for (int p = 0; p < P; ++p) {
        const float lu = __builtin_amdgcn_logf(fmaxf(tt[p], 1e-30f));
        const float lv = __builtin_amdgcn_logf(fmaxf(1.0f - tt[p], 1e-30f));
        dd[p] = lu - lv;
        e0[p] = 31.0f * lv;
    }
    float4 ex[GB], ey[GB];
#pragma unroll
    for (int g = 0; g < GB; ++g) {
        ex[g] = make_float4(0.f, 0.f, 0.f, 0.f);
        ey[g] = make_float4(0.f, 0.f, 0.f, 0.f);
    }
#pragma unroll
    for (int i = 0; i < NCP; i += 2) {
        float ba[P], bb[P];
#pragma unroll
        for (int p = 0; p < P; ++p) {
            ba[p] = C31[i]     * __builtin_amdgcn_exp2f(fmaf((float)i,       dd[p], e0[p]));
            bb[p] = C31[i + 1] * __builtin_amdgcn_exp2f(fmaf((float)(i + 1), dd[p], e0[p]));
        }
#pragma unroll
        for (int g = 0; g < GB; ++g) {
            // wave-uniform broadcast: byte offset 256*g + 8*i, 16B-aligned
            float4 c = *reinterpret_cast<const float4*>(&s_bz[g * 64 + 2 * i]);
            float* exp_ = reinterpret_cast<float*>(&ex[g]);
            float* eyp_ = reinterpret_cast<float*>(&ey[g]);
#pragma unroll
            for (int p = 0; p < P; ++p) {
                exp_[p] = fmaf(ba[p], c.x, fmaf(bb[p], c.z, exp_[p]));
                eyp_[p] = fmaf(ba[p], c.y, fmaf(bb[p], c.w, eyp_[p]));
            }
        }
    }
#pragma unroll
    for (int g = 0; g < GB; ++g) {
        const unsigned base = 2u * cs + (unsigned)(b0 + g) * 2u * NPTS + (unsigned)n0;
        *reinterpret_cast<float4*>(&out[base])        = ex[g];
        *reinterpret_cast<float4*>(&out[base + NPTS]) = ey[g];
    }
}

extern "C" void kernel_launch(void* const* d_in, const int* in_sizes, int n_in,
                              void* d_out, int out_size, void* d_ws, size_t ws_size,
                              hipStream_t stream) {
    const float* bspline_cp = (const float*)d_in[0];
    const float* nurbs_cp   = (const float*)d_in[1];
    const float* nurbs_w    = (const float*)d_in[2];
    const float* bezier_cp  = (const float*)d_in[3];
    float* out = (float*)d_out;

    const int B = in_sizes[2] / NCP;              // 2048

    hipLaunchKernelGGL(fused_kernel, dim3(NPTS / (256 * P), B / GB), dim3(256), 0, stream,
                       bspline_cp, nurbs_cp, nurbs_w, bezier_cp, out, B);
}

// Round 6
// 32.880 us; speedup vs baseline: 2.8278x; 2.8278x over previous
//
#include <hip/hip_runtime.h>

#define NPTS 2048
#define NCP  32
#define P    4   // consecutive points per thread (float4 stores)
#define GB   2   // batches per block

// Binomial coefficients C(31, i) (exact)
static __device__ const float C31[NCP] = {
    1.f, 31.f, 465.f, 4495.f, 31465.f, 169911.f, 736281.f, 2629575.f,
    7888725.f, 20160075.f, 44352165.f, 84672315.f, 141120525.f, 206253075.f,
    265182525.f, 300540195.f, 300540195.f, 265182525.f, 206253075.f, 141120525.f,
    84672315.f, 44352165.f, 20160075.f, 7888725.f, 2629575.f, 736281.f,
    169911.f, 31465.f, 4495.f, 465.f, 31.f, 1.f
};

// Clamped knot vector value for knot index i (0..35): 4 zeros, interior
// (i-3)/29, 4 ones.
__device__ __forceinline__ float knq(int i) {
    int m = i - 3;
    m = m < 0 ? 0 : m;
    return (m >= 29) ? 1.0f : (float)m * (float)(1.0 / 29.0);
}

// P=4 points x GB=2 batches per thread: each wave-uniform broadcast
// ds_read_b128 feeds FMAs for 4 points (bezier DS: 16 -> 4 instr per
// point-batch vs P=1). launch_bounds(256,6): VGPR cap ~85 comfortably holds
// the ~70-reg live set -> NO scratch spill (R5's failure mode), 6 waves/SIMD.
// Stores assembled via make_float4 from constant-indexed scalars (no
// address-taken aggregates).
__global__ void __launch_bounds__(256, 6) fused_kernel(
    const float* __restrict__ bspline_cp, const float* __restrict__ nurbs_cp,
    const float* __restrict__ nurbs_w, const float* __restrict__ bezier_cp,
    float* __restrict__ out, int B) {
    const int tid = threadIdx.x;
    const int n0  = (blockIdx.x * 256 + tid) * P;   // first of this thread's 4 points
    const int b0  = blockIdx.y * GB;

    __shared__ float s_bs[GB * NCP * 2];
    __shared__ float s_nc[GB * NCP * 2];
    __shared__ float s_bz[GB * NCP * 2];
    __shared__ float s_w [GB * NCP];
    if (tid < GB * NCP * 2) {                       // 128 < 256: one pass
        s_bs[tid] = bspline_cp[(size_t)b0 * NCP * 2 + tid];
        s_nc[tid] = nurbs_cp [(size_t)b0 * NCP * 2 + tid];
        s_bz[tid] = bezier_cp[(size_t)b0 * NCP * 2 + tid];
    }
    if (tid < GB * NCP)
        s_w[tid] = nurbs_w[(size_t)b0 * NCP + tid];
    __syncthreads();

    const unsigned cs = (unsigned)B * 2u * NPTS;    // per-curve output stride

    // ---- Phase A: per-point t, span, cubic de Boor basis ----
    float tt[P];
    int   sp_[P];
    float bv[P][4];
#pragma unroll
    for (int p = 0; p < P; ++p) {
        const float t = (float)((double)(n0 + p) * (1.0 / (double)(NPTS - 1)));
        tt[p] = t;
        int s = (int)(t * 29.0f);
        s = s < 28 ? s : 28;
        sp_[p] = s;
        const int j = s + 3;             // knot-span: U[j] <= t < U[j+1]
        const float L1 = t - knq(j);
        const float R1 = knq(j + 1) - t;
        const float L2 = t - knq(j - 1);
        const float R2 = knq(j + 2) - t;
        const float L3 = t - knq(j - 2);
        const float R3 = knq(j + 3) - t;
        float N0, N1, N2, N3, tmp, sv;
        tmp = __builtin_amdgcn_rcpf(R1 + L1);
        N0 = R1 * tmp;
        N1 = L1 * tmp;
        tmp = N0 * __builtin_amdgcn_rcpf(R1 + L2);
        N0 = R1 * tmp;
        sv = L2 * tmp;
        tmp = N1 * __builtin_amdgcn_rcpf(R2 + L1);
        N1 = fmaf(R2, tmp, sv);
        N2 = L1 * tmp;
        tmp = N0 * __builtin_amdgcn_rcpf(R1 + L3);
        N0 = R1 * tmp;
        sv = L3 * tmp;
        tmp = N1 * __builtin_amdgcn_rcpf(R2 + L2);
        N1 = fmaf(R2, tmp, sv);
        sv = L2 * tmp;
        tmp = N2 * __builtin_amdgcn_rcpf(R3 + L1);
        N2 = fmaf(R3, tmp, sv);
        N3 = L1 * tmp;
        bv[p][0] = N0; bv[p][1] = N1; bv[p][2] = N2; bv[p][3] = N3;
    }

    // ---- Phase B: B-spline + NURBS sparse 4-term dots, streamed per g ----
#pragma unroll
    for (int g = 0; g < GB; ++g) {
        float obx[P], oby[P], onx[P], ony[P];
#pragma unroll
        for (int p = 0; p < P; ++p) {
            float sbx = 0.f, sby = 0.f, snx = 0.f, sny = 0.f, den = 0.f;
#pragma unroll
            for (int k = 0; k < 4; ++k) {
                const int idx = sp_[p] + k;
                const float c = bv[p][k];
                float2 cb = *reinterpret_cast<const float2*>(&s_bs[g * 64 + idx * 2]);
                sbx = fmaf(c, cb.x, sbx); sby = fmaf(c, cb.y, sby);
                const float wb = c * s_w[g * 32 + idx];
                den += wb;
                float2 cn = *reinterpret_cast<const float2*>(&s_nc[g * 64 + idx * 2]);
                snx = fmaf(wb, cn.x, snx); sny = fmaf(wb, cn.y, sny);
            }
            const float inv = __builtin_amdgcn_rcpf(den + 1e-8f);
            obx[p] = sbx; oby[p] = sby;
            onx[p] = snx * inv; ony[p] = sny * inv;
        }
        const unsigned base = (unsigned)(b0 + g) * 2u * NPTS + (unsigned)n0;
        *reinterpret_cast<float4*>(&out[base]) =
            make_float4(obx[0], obx[1], obx[2], obx[3]);
        *reinterpret_cast<float4*>(&out[base + NPTS]) =
            make_float4(oby[0], oby[1], oby[2], oby[3]);
        *reinterpret_cast<float4*>(&out[cs + base]) =
            make_float4(onx[0], onx[1], onx[2], onx[3]);
        *reinterpret_cast<float4*>(&out[cs + base + NPTS]) =
            make_float4(ony[0], ony[1], ony[2], ony[3]);
    }

    // ---- Phase C: Bezier dense 32-term dot; basis exp2-in-register ----
    float dd[P], e0[P];
#pragma unroll
    for (int p = 0; p < P; ++p) {
        const float lu = __builtin_amdgcn_logf(fmaxf(tt[p], 1e-30f));
        const float lv = __builtin_amdgcn_logf(fmaxf(1.0f - tt[p], 1e-30f));
        dd[p] = lu - lv;
        e0[p] = 31.0f * lv;
    }
    float ex[GB][P], ey[GB][P];
#pragma unroll
    for (int g = 0; g < GB; ++g)
#pragma unroll
        for (int p = 0; p < P; ++p) { ex[g][p] = 0.f; ey[g][p] = 0.f; }
#pragma unroll
    for (int i = 0; i < NCP; i += 2) {
        float ba[P], bb[P];
#pragma unroll
        for (int p = 0; p < P; ++p) {
            ba[p] = C31[i]     * __builtin_amdgcn_exp2f(fmaf((float)i,       dd[p], e0[p]));
            bb[p] = C31[i + 1] * __builtin_amdgcn_exp2f(fmaf((float)(i + 1), dd[p], e0[p]));
        }
#pragma unroll
        for (int g = 0; g < GB; ++g) {
            // wave-uniform broadcast: byte offset 256*g + 8*i (i even) -> 16B-aligned
            float4 c = *reinterpret_cast<const float4*>(&s_bz[g * 64 + 2 * i]);
#pragma unroll
            for (int p = 0; p < P; ++p) {
                ex[g][p] = fmaf(ba[p], c.x, fmaf(bb[p], c.z, ex[g][p]));
                ey[g][p] = fmaf(ba[p], c.y, fmaf(bb[p], c.w, ey[g][p]));
            }
        }
    }
#pragma unroll
    for (int g = 0; g < GB; ++g) {
        const unsigned base = 2u * cs + (unsigned)(b0 + g) * 2u * NPTS + (unsigned)n0;
        *reinterpret_cast<float4*>(&out[base]) =
            make_float4(ex[g][0], ex[g][1], ex[g][2], ex[g][3]);
        *reinterpret_cast<float4*>(&out[base + NPTS]) =
            make_float4(ey[g][0], ey[g][1], ey[g][2], ey[g][3]);
    }
}

extern "C" void kernel_launch(void* const* d_in, const int* in_sizes, int n_in,
                              void* d_out, int out_size, void* d_ws, size_t ws_size,
                              hipStream_t stream) {
    const float* bspline_cp = (const float*)d_in[0];
    const float* nurbs_cp   = (const float*)d_in[1];
    const float* nurbs_w    = (const float*)d_in[2];
    const float* bezier_cp  = (const float*)d_in[3];
    float* out = (float*)d_out;

    const int B = in_sizes[2] / NCP;              // 2048

    hipLaunchKernelGGL(fused_kernel, dim3(NPTS / (256 * P), B / GB), dim3(256), 0, stream,
                       bspline_cp, nurbs_cp, nurbs_w, bezier_cp, out, B);
}